// Round 1
// baseline (800.942 us; speedup 1.0000x reference)
//
#include <hip/hip_runtime.h>
#include <stdint.h>

#define HID 128
#define EDIM 32

typedef __attribute__((ext_vector_type(8))) short bf16x8;
typedef __attribute__((ext_vector_type(4))) float f4_t;

static __device__ __forceinline__ unsigned short f2bf(float f) {
  union { float f; unsigned int u; } v; v.f = f;
  return (unsigned short)((v.u + 0x7fffu + ((v.u >> 16) & 1u)) >> 16);
}

static __device__ __forceinline__ void atomAddF(float* p, float v) {
#if defined(__gfx950__) || defined(__gfx942__) || defined(__gfx90a__)
  unsafeAtomicAdd(p, v);
#else
  atomicAdd(p, v);
#endif
}

// ---------------------------------------------------------------------------
// Edge pass: e = edge_attr @ W + b ; msg = relu(x[src] + e) ; agg[dst] += msg
// One wave handles a 16-edge tile; K=32 -> exactly one MFMA per 16-ch slice.
// ---------------------------------------------------------------------------
__global__ __launch_bounds__(256) void edge_kernel(
    const float* __restrict__ x, const int* __restrict__ ei,
    const float* __restrict__ ea, const float* __restrict__ W,
    const float* __restrict__ bias, float* __restrict__ agg,
    int nE, int nTiles) {
  const int lane = threadIdx.x & 63;
  const int l15 = lane & 15;
  const int lq  = lane >> 4;

  // W fragments in registers: lane holds W[8*lq+j][16*nt+l15], j=0..7
  bf16x8 Wf[8];
  float bv[8];
#pragma unroll
  for (int nt = 0; nt < 8; ++nt) {
#pragma unroll
    for (int j = 0; j < 8; ++j)
      Wf[nt][j] = (short)f2bf(W[(8 * lq + j) * HID + 16 * nt + l15]);
    bv[nt] = bias[16 * nt + l15];
  }

  const int wavesPerBlk = blockDim.x >> 6;
  int waveId = blockIdx.x * wavesPerBlk + ((int)threadIdx.x >> 6);
  const int nWaves = gridDim.x * wavesPerBlk;

  for (int tile = waveId; tile < nTiles; tile += nWaves) {
    const int e0 = tile << 4;
    int er = e0 + l15; if (er >= nE) er = nE - 1;
    // A fragment: ea[er][8*lq .. 8*lq+7]
    const float* ap = ea + (size_t)er * EDIM + 8 * lq;
    f4_t a0 = *(const f4_t*)ap;
    f4_t a1 = *(const f4_t*)(ap + 4);
    bf16x8 af;
#pragma unroll
    for (int j = 0; j < 4; ++j) { af[j] = (short)f2bf(a0[j]); af[j + 4] = (short)f2bf(a1[j]); }

    f4_t acc[8];
#pragma unroll
    for (int nt = 0; nt < 8; ++nt) {
      f4_t c; c[0] = bv[nt]; c[1] = bv[nt]; c[2] = bv[nt]; c[3] = bv[nt];
      acc[nt] = __builtin_amdgcn_mfma_f32_16x16x32_bf16(af, Wf[nt], c, 0, 0, 0);
    }

    // Epilogue: lane owns edges e0+lq*4+r (r=0..3), channel l15+16*nt
#pragma unroll
    for (int r = 0; r < 4; ++r) {
      const int e = e0 + lq * 4 + r;
      if (e < nE) {
        const int s = ei[e];
        const int d = ei[nE + e];
        const float* xp = x + (size_t)s * HID + l15;
        float* gp = agg + (size_t)d * HID + l15;
#pragma unroll
        for (int nt = 0; nt < 8; ++nt) {
          float m = acc[nt][r] + xp[nt * 16];
          atomAddF(gp + nt * 16, fmaxf(m, 0.f));
        }
      }
    }
  }
}

// ---------------------------------------------------------------------------
// Node pass: h = agg + x ; h1 = relu(h@W1+b1) ; h2 = h1@W2+b2 -> d_out
// plus per-column sum / sumsq accumulation for GraphNorm.
// W1^T / W2^T in LDS (bf16, XOR-swizzled 16B granules); per-wave LDS
// roundtrip to re-fragment h1 as the A operand of GEMM2.
// ---------------------------------------------------------------------------
__global__ __launch_bounds__(256) void node_kernel(
    const float* __restrict__ x, const float* __restrict__ agg,
    const float* __restrict__ W1, const float* __restrict__ b1,
    const float* __restrict__ W2, const float* __restrict__ b2,
    float* __restrict__ h2out, float* __restrict__ stats,
    int nNodes, int nTiles) {
  __shared__ unsigned short sW1[128 * 128];
  __shared__ unsigned short sW2[128 * 128];
  __shared__ unsigned short sH1[4][16 * 128];

  // Fill W^T LDS, swizzled: element (n,k) at n*128 + ((k>>3 ^ (n&15))<<3) + (k&7)
  for (int idx = threadIdx.x; idx < 128 * 128; idx += 256) {
    int n = idx & 127, k = idx >> 7;
    int off = n * 128 + ((((k >> 3) ^ (n & 15))) << 3) + (k & 7);
    sW1[off] = f2bf(W1[k * HID + n]);
    sW2[off] = f2bf(W2[k * HID + n]);
  }
  __syncthreads();

  const int lane = threadIdx.x & 63;
  const int l15 = lane & 15, lq = lane >> 4;
  const int wv = threadIdx.x >> 6;
  unsigned short* hb = &sH1[wv][0];

  float b1v[8], b2v[8];
#pragma unroll
  for (int nt = 0; nt < 8; ++nt) { b1v[nt] = b1[nt * 16 + l15]; b2v[nt] = b2[nt * 16 + l15]; }
  float ssum[8] = {0, 0, 0, 0, 0, 0, 0, 0};
  float ssq[8]  = {0, 0, 0, 0, 0, 0, 0, 0};

  int waveId = blockIdx.x * 4 + wv;
  const int nWaves = gridDim.x * 4;

  for (int tile = waveId; tile < nTiles; tile += nWaves) {
    const int r0 = tile << 4;
    int rr = r0 + l15; if (rr >= nNodes) rr = nNodes - 1;
    const float* hp1 = agg + (size_t)rr * HID;
    const float* hp2 = x + (size_t)rr * HID;

    bf16x8 af[4];
#pragma unroll
    for (int kt = 0; kt < 4; ++kt) {
      const int k0 = kt * 32 + 8 * lq;
      f4_t u0 = *(const f4_t*)(hp1 + k0);
      f4_t u1 = *(const f4_t*)(hp1 + k0 + 4);
      f4_t v0 = *(const f4_t*)(hp2 + k0);
      f4_t v1 = *(const f4_t*)(hp2 + k0 + 4);
#pragma unroll
      for (int j = 0; j < 4; ++j) {
        af[kt][j]     = (short)f2bf(u0[j] + v0[j]);
        af[kt][j + 4] = (short)f2bf(u1[j] + v1[j]);
      }
    }

    // GEMM1
    f4_t acc[8];
#pragma unroll
    for (int nt = 0; nt < 8; ++nt) {
      f4_t c; c[0] = b1v[nt]; c[1] = b1v[nt]; c[2] = b1v[nt]; c[3] = b1v[nt];
#pragma unroll
      for (int kt = 0; kt < 4; ++kt) {
        bf16x8 wf = *(const bf16x8*)&sW1[(nt * 16 + l15) * 128 + ((((kt * 4 + lq) ^ l15)) << 3)];
        c = __builtin_amdgcn_mfma_f32_16x16x32_bf16(af[kt], wf, c, 0, 0, 0);
      }
      acc[nt] = c;
    }

    // relu(h1) -> per-wave LDS (swizzled row-major [16][128] bf16)
#pragma unroll
    for (int nt = 0; nt < 8; ++nt) {
      const int ghi = 2 * nt + (l15 >> 3);
#pragma unroll
      for (int r = 0; r < 4; ++r) {
        const int row = lq * 4 + r;
        hb[row * 128 + ((ghi ^ (row & 15)) << 3) + (l15 & 7)] = f2bf(fmaxf(acc[nt][r], 0.f));
      }
    }
    asm volatile("s_waitcnt lgkmcnt(0)" ::: "memory");
    __builtin_amdgcn_sched_barrier(0);

    bf16x8 af2[4];
#pragma unroll
    for (int kt = 0; kt < 4; ++kt)
      af2[kt] = *(const bf16x8*)&hb[l15 * 128 + ((((kt * 4 + lq) ^ l15)) << 3)];

    // GEMM2
    f4_t acc2[8];
#pragma unroll
    for (int nt = 0; nt < 8; ++nt) {
      f4_t c; c[0] = b2v[nt]; c[1] = b2v[nt]; c[2] = b2v[nt]; c[3] = b2v[nt];
#pragma unroll
      for (int kt = 0; kt < 4; ++kt) {
        bf16x8 wf = *(const bf16x8*)&sW2[(nt * 16 + l15) * 128 + ((((kt * 4 + lq) ^ l15)) << 3)];
        c = __builtin_amdgcn_mfma_f32_16x16x32_bf16(af2[kt], wf, c, 0, 0, 0);
      }
      acc2[nt] = c;
    }

    // write h2 + accumulate stats
#pragma unroll
    for (int nt = 0; nt < 8; ++nt) {
#pragma unroll
      for (int r = 0; r < 4; ++r) {
        const int row = r0 + lq * 4 + r;
        if (row < nNodes) {
          float v = acc2[nt][r];
          h2out[(size_t)row * HID + nt * 16 + l15] = v;
          ssum[nt] += v; ssq[nt] += v * v;
        }
      }
    }
  }

  // reduce stats across the 4 sixteen-lane groups, one atomic per column/wave
#pragma unroll
  for (int nt = 0; nt < 8; ++nt) {
    float a = ssum[nt], b = ssq[nt];
    a += __shfl_xor(a, 16); b += __shfl_xor(b, 16);
    a += __shfl_xor(a, 32); b += __shfl_xor(b, 32);
    if (lq == 0) {
      atomAddF(&stats[nt * 16 + l15], a);
      atomAddF(&stats[HID + nt * 16 + l15], b);
    }
  }
}

// ---------------------------------------------------------------------------
// Fold GraphNorm into per-column affine: out = relu(A*h2 + B)
// var = E[(h - s*m)^2] = msq - (2s - s^2) m^2
// ---------------------------------------------------------------------------
__global__ void norm_prep(float* __restrict__ stats, const float* __restrict__ gw,
                          const float* __restrict__ gb, const float* __restrict__ gs,
                          int nNodes) {
  int c = threadIdx.x;
  if (c < HID) {
    float invN = 1.f / (float)nNodes;
    float m   = stats[c] * invN;
    float msq = stats[HID + c] * invN;
    float s   = gs[c];
    float var = msq - (2.f * s - s * s) * m * m;
    float A = gw[c] * rsqrtf(var + 1e-5f);
    float B = gb[c] - A * s * m;
    stats[2 * HID + c] = A;
    stats[3 * HID + c] = B;
  }
}

__global__ __launch_bounds__(256) void norm_kernel(const float* __restrict__ stats,
                                                   float* __restrict__ out, int total4) {
  const f4_t* A4 = (const f4_t*)(stats + 2 * HID);
  const f4_t* B4 = (const f4_t*)(stats + 3 * HID);
  int i = blockIdx.x * blockDim.x + threadIdx.x;
  const int stride = gridDim.x * blockDim.x;
  for (; i < total4; i += stride) {
    const int cg = i & 31;
    f4_t h = ((const f4_t*)out)[i];
    f4_t a = A4[cg], b = B4[cg];
    f4_t o;
#pragma unroll
    for (int j = 0; j < 4; ++j) o[j] = fmaxf(fmaf(h[j], a[j], b[j]), 0.f);
    ((f4_t*)out)[i] = o;
  }
}

extern "C" void kernel_launch(void* const* d_in, const int* in_sizes, int n_in,
                              void* d_out, int out_size, void* d_ws, size_t ws_size,
                              hipStream_t stream) {
  const float* x  = (const float*)d_in[0];
  const int*   ei = (const int*)d_in[1];
  const float* ea = (const float*)d_in[2];
  const float* eW = (const float*)d_in[3];
  const float* eb = (const float*)d_in[4];
  const float* W1 = (const float*)d_in[5];
  const float* b1 = (const float*)d_in[6];
  const float* W2 = (const float*)d_in[7];
  const float* b2 = (const float*)d_in[8];
  const float* gw = (const float*)d_in[9];
  const float* gb = (const float*)d_in[10];
  const float* gs = (const float*)d_in[11];
  float* out = (float*)d_out;

  const int nNodes = in_sizes[0] / HID;   // 100000
  const int nE     = in_sizes[1] / 2;     // 1600000

  const size_t aggBytes = (size_t)nNodes * HID * sizeof(float);
  float* agg   = (float*)d_ws;
  float* stats = (float*)((char*)d_ws + aggBytes);

  hipMemsetAsync(d_ws, 0, aggBytes + 4 * HID * sizeof(float), stream);

  const int eTiles = (nE + 15) >> 4;
  edge_kernel<<<2048, 256, 0, stream>>>(x, ei, ea, eW, eb, agg, nE, eTiles);

  const int nTiles = (nNodes + 15) >> 4;
  node_kernel<<<782, 256, 0, stream>>>(x, agg, W1, b1, W2, b2, out, stats, nNodes, nTiles);

  norm_prep<<<1, 128, 0, stream>>>(stats, gw, gb, gs, nNodes);
  norm_kernel<<<2048, 256, 0, stream>>>(stats, out, nNodes * (HID / 4));
}